// Round 5
// baseline (76.451 us; speedup 1.0000x reference)
//
#include <hip/hip_runtime.h>
#include <hip/hip_bf16.h>
#include <math.h>

#define BATCH 4
#define CDIM 256
#define NDIM 4096
#define CLD 32
#define EPSBN 1e-5f
#define SPLITS 8
#define KEYS_PER_WAVE (NDIM / SPLITS)   // 512
#define LOG2E 1.4426950408889634f

typedef unsigned short u16;
typedef unsigned int u32;
typedef __attribute__((ext_vector_type(8))) short bf16x8;   // 8 bf16 = 4 VGPR MFMA operand
typedef __attribute__((ext_vector_type(16))) float f32x16;  // 32x32 MFMA accumulator
typedef __attribute__((ext_vector_type(4))) u32 u32x4;
typedef __attribute__((ext_vector_type(2))) u32 u32x2;

__device__ inline u16 f2bf(float x) {
    return __builtin_bit_cast(u16, __float2bfloat16(x));
}
__device__ inline u32 pack_bf16x2(float a, float b) {
    return (u32)f2bf(a) | ((u32)f2bf(b) << 16);
}
__device__ inline bf16x8 pack8(float4 a, float4 b) {
    u32x4 u;
    u.x = pack_bf16x2(a.x, a.y); u.y = pack_bf16x2(a.z, a.w);
    u.z = pack_bf16x2(b.x, b.y); u.w = pack_bf16x2(b.z, b.w);
    return __builtin_bit_cast(bf16x8, u);
}

// ---------------- Kernel 1: QKV projection + BN + ReLU -> bf16 ----------------
// grid (N/128, B, 6), block 256 = 4 waves. Wave g = z*4+w owns 4 channels of one
// of {w1,w2,w3} x 128 n. Weights via uniform s_load; x via float2 vmem.
// q (scaled by log2e), k -> [B][N][32] bf16 ; v -> [B][32][N] bf16.
__global__ __launch_bounds__(256) void proj_qkv(
    const float* __restrict__ x,
    const float* __restrict__ w1, const float* __restrict__ w2, const float* __restrict__ w3,
    const float* __restrict__ b1s, const float* __restrict__ b1b, const float* __restrict__ b1m, const float* __restrict__ b1v,
    const float* __restrict__ b2s, const float* __restrict__ b2b, const float* __restrict__ b2m, const float* __restrict__ b2v,
    const float* __restrict__ b3s, const float* __restrict__ b3b, const float* __restrict__ b3m, const float* __restrict__ b3v,
    u16* __restrict__ qo, u16* __restrict__ ko, u16* __restrict__ vo)
{
    const int tid  = threadIdx.x;
    const int lane = tid & 63;
    const int b    = blockIdx.y;
    const int g    = __builtin_amdgcn_readfirstlane(blockIdx.z * 4 + (tid >> 6)); // 0..23 uniform
    const int mat  = g >> 3;             // 0:q/w1 1:k/w2 2:v/w3
    const int ch0  = (g & 7) * 4;
    const int n    = blockIdx.x * 128 + lane * 2;

    const float* wb = ((mat == 0) ? w1 : (mat == 1) ? w2 : w3) + (size_t)ch0 * CDIM;

    float2 acc[4];
#pragma unroll
    for (int o = 0; o < 4; ++o) acc[o] = make_float2(0.f, 0.f);

    const float* xb = x + (size_t)b * CDIM * NDIM + n;

#pragma unroll 4
    for (int c = 0; c < CDIM; c += 4) {
        float4 wq[4];
#pragma unroll
        for (int o = 0; o < 4; ++o)
            wq[o] = *reinterpret_cast<const float4*>(wb + o * CDIM + c);  // uniform -> s_load
        float2 xv[4];
#pragma unroll
        for (int cc = 0; cc < 4; ++cc)
            xv[cc] = *reinterpret_cast<const float2*>(xb + (size_t)(c + cc) * NDIM);
#pragma unroll
        for (int cc = 0; cc < 4; ++cc) {
#pragma unroll
            for (int o = 0; o < 4; ++o) {
                float wv = (cc == 0) ? wq[o].x : (cc == 1) ? wq[o].y : (cc == 2) ? wq[o].z : wq[o].w;
                acc[o].x = fmaf(wv, xv[cc].x, acc[o].x);
                acc[o].y = fmaf(wv, xv[cc].y, acc[o].y);
            }
        }
    }

    const float* ps = (mat == 0) ? b1s : (mat == 1) ? b2s : b3s;
    const float* pb = (mat == 0) ? b1b : (mat == 1) ? b2b : b3b;
    const float* pm = (mat == 0) ? b1m : (mat == 1) ? b2m : b3m;
    const float* pv = (mat == 0) ? b1v : (mat == 1) ? b2v : b3v;
    const float qscale = (mat == 0) ? LOG2E : 1.0f;

    float y0[4], y1[4];
#pragma unroll
    for (int o = 0; o < 4; ++o) {
        float inv = ps[ch0 + o] / sqrtf(pv[ch0 + o] + EPSBN);
        float mb  = pm[ch0 + o];
        float bb  = pb[ch0 + o];
        y0[o] = fmaxf((acc[o].x - mb) * inv + bb, 0.f) * qscale;
        y1[o] = fmaxf((acc[o].y - mb) * inv + bb, 0.f) * qscale;
    }

    if (mat < 2) {
        u16* dst = ((mat == 0) ? qo : ko) + ((size_t)b * NDIM + n) * CLD + ch0;
        u32x2 s0, s1;
        s0.x = pack_bf16x2(y0[0], y0[1]); s0.y = pack_bf16x2(y0[2], y0[3]);
        s1.x = pack_bf16x2(y1[0], y1[1]); s1.y = pack_bf16x2(y1[2], y1[3]);
        *reinterpret_cast<u32x2*>(dst)       = s0;
        *reinterpret_cast<u32x2*>(dst + CLD) = s1;
    } else {
#pragma unroll
        for (int o = 0; o < 4; ++o)
            *reinterpret_cast<u32*>(vo + ((size_t)b * CLD + ch0 + o) * NDIM + n) = pack_bf16x2(y0[o], y1[o]);
    }
}

// p[16] (keys (r&3)+8*(r>>2)+4*hi of a 32-key tile) -> PV B-fragments pf0/pf1
// (frag0: keys 8*hi+i ; frag1: keys 16+8*hi+i). Verified layout (rounds 1-4).
__device__ inline void pack_p(const float* p, int hi, bf16x8& pf0, bf16x8& pf1) {
    u32 bw[8], bx[8];
#pragma unroll
    for (int t = 0; t < 8; ++t) bw[t] = pack_bf16x2(p[2 * t], p[2 * t + 1]);
#pragma unroll
    for (int t = 0; t < 8; ++t) bx[t] = (u32)__shfl_xor((int)bw[t], 32);
    u32x4 f0u, f1u;
    f0u.x = hi ? bx[2] : bw[0];  f0u.y = hi ? bx[3] : bw[1];
    f0u.z = hi ? bw[2] : bx[0];  f0u.w = hi ? bw[3] : bx[1];
    f1u.x = hi ? bx[6] : bw[4];  f1u.y = hi ? bx[7] : bw[5];
    f1u.z = hi ? bw[6] : bx[4];  f1u.w = hi ? bw[7] : bx[5];
    pf0 = __builtin_bit_cast(bf16x8, f0u);
    pf1 = __builtin_bit_cast(bf16x8, f1u);
}

// ---------------- Kernel 2: MFMA flash attention, 8-way split-in-block ----------------
// grid (N/32, B), block 512 = 8 waves; all waves share one 32-query tile, each
// owns 512 keys. Scores arrive in log2 domain (q pre-scaled by log2e).
// LDS combine writes agg bf16 [B][N][32] directly.
__global__ __launch_bounds__(512, 4) void attn_mfma(
    const u16* __restrict__ q, const u16* __restrict__ k, const u16* __restrict__ v,
    u16* __restrict__ agg)
{
    __shared__ float o_lds[SPLITS][32][32];   // 32 KB
    __shared__ float m_lds[SPLITS][32];
    __shared__ float l_lds[SPLITS][32];

    const int tid  = threadIdx.x;
    const int lane = tid & 63;
    const int w    = tid >> 6;            // split 0..7
    const int b    = blockIdx.y;
    const int q0   = blockIdx.x * 32;
    const int col  = lane & 31;
    const int hi   = lane >> 5;

    const u16* qp = q + ((size_t)b * NDIM + q0 + col) * CLD + 8 * hi;
    bf16x8 qf0 = *reinterpret_cast<const bf16x8*>(qp);
    bf16x8 qf1 = *reinterpret_cast<const bf16x8*>(qp + 16);

    f32x16 o = {0.f,0.f,0.f,0.f, 0.f,0.f,0.f,0.f, 0.f,0.f,0.f,0.f, 0.f,0.f,0.f,0.f};
    float m_run = -3e38f, l_run = 0.f;

    const int kstart = w * KEYS_PER_WAVE;
    const u16* kb = k + (size_t)b * NDIM * CLD;
    const u16* vb = v + (size_t)b * CLD * NDIM + (size_t)col * NDIM;

    for (int kt = 0; kt < KEYS_PER_WAVE; kt += 64) {
        const int k0 = kstart + kt;
        // ---- QK^T for two 32-key tiles ----
        const u16* kpA = kb + (size_t)(k0 + col) * CLD + 8 * hi;
        bf16x8 kfA0 = *reinterpret_cast<const bf16x8*>(kpA);
        bf16x8 kfA1 = *reinterpret_cast<const bf16x8*>(kpA + 16);
        const u16* kpB = kpA + 32 * CLD;
        bf16x8 kfB0 = *reinterpret_cast<const bf16x8*>(kpB);
        bf16x8 kfB1 = *reinterpret_cast<const bf16x8*>(kpB + 16);

        f32x16 sa = {0.f,0.f,0.f,0.f, 0.f,0.f,0.f,0.f, 0.f,0.f,0.f,0.f, 0.f,0.f,0.f,0.f};
        f32x16 sb = {0.f,0.f,0.f,0.f, 0.f,0.f,0.f,0.f, 0.f,0.f,0.f,0.f, 0.f,0.f,0.f,0.f};
        sa = __builtin_amdgcn_mfma_f32_32x32x16_bf16(kfA0, qf0, sa, 0, 0, 0);
        sa = __builtin_amdgcn_mfma_f32_32x32x16_bf16(kfA1, qf1, sa, 0, 0, 0);
        sb = __builtin_amdgcn_mfma_f32_32x32x16_bf16(kfB0, qf0, sb, 0, 0, 0);
        sb = __builtin_amdgcn_mfma_f32_32x32x16_bf16(kfB1, qf1, sb, 0, 0, 0);

        // ---- online softmax over 64 keys (log2 domain) ----
        float tmax = fmaxf(sa[0], sb[0]);
#pragma unroll
        for (int r = 1; r < 16; ++r) tmax = fmaxf(tmax, fmaxf(sa[r], sb[r]));
        tmax = fmaxf(tmax, __shfl_xor(tmax, 32));

        if (__any(tmax > m_run)) {       // exact skip: else-path is all identity ops
            float mnew = fmaxf(m_run, tmax);
            float f = exp2f(m_run - mnew);
            l_run *= f;
            m_run = mnew;
#pragma unroll
            for (int r = 0; r < 16; ++r) o[r] *= f;
        }

        float psum = 0.f;
#pragma unroll
        for (int r = 0; r < 16; ++r) { sa[r] = exp2f(sa[r] - m_run); psum += sa[r]; }
#pragma unroll
        for (int r = 0; r < 16; ++r) { sb[r] = exp2f(sb[r] - m_run); psum += sb[r]; }
        psum += __shfl_xor(psum, 32);
        l_run += psum;

        // ---- PV for both tiles ----
        const u16* vp = vb + k0 + 8 * hi;
        bf16x8 vfA0 = *reinterpret_cast<const bf16x8*>(vp);
        bf16x8 vfA1 = *reinterpret_cast<const bf16x8*>(vp + 16);
        bf16x8 vfB0 = *reinterpret_cast<const bf16x8*>(vp + 32);
        bf16x8 vfB1 = *reinterpret_cast<const bf16x8*>(vp + 48);

        float pa[16], pbv[16];
#pragma unroll
        for (int r = 0; r < 16; ++r) { pa[r] = sa[r]; pbv[r] = sb[r]; }
        bf16x8 pf0, pf1;
        pack_p(pa, hi, pf0, pf1);
        o = __builtin_amdgcn_mfma_f32_32x32x16_bf16(vfA0, pf0, o, 0, 0, 0);
        o = __builtin_amdgcn_mfma_f32_32x32x16_bf16(vfA1, pf1, o, 0, 0, 0);
        pack_p(pbv, hi, pf0, pf1);
        o = __builtin_amdgcn_mfma_f32_32x32x16_bf16(vfB0, pf0, o, 0, 0, 0);
        o = __builtin_amdgcn_mfma_f32_32x32x16_bf16(vfB1, pf1, o, 0, 0, 0);
    }

    // ---- publish partials ----
#pragma unroll
    for (int r = 0; r < 16; ++r) {
        int d = (r & 3) + 8 * (r >> 2) + 4 * hi;
        o_lds[w][d][col] = o[r];
    }
    if (hi == 0) { m_lds[w][col] = m_run; l_lds[w][col] = l_run; }
    __syncthreads();

    // ---- combine 8 splits -> agg bf16 [B][N][32] ----
    // thread: qq = tid>>4 (0..31), dp = tid&15 (d-pair) -> consecutive lanes
    // write consecutive u32 along d.
    {
        const int qq = tid >> 4;
        const int dp = tid & 15;
        float ms[SPLITS];
        float mstar = -3e38f;
#pragma unroll
        for (int s = 0; s < SPLITS; ++s) { ms[s] = m_lds[s][qq]; mstar = fmaxf(mstar, ms[s]); }
        float wn[SPLITS];
        float den = 0.f;
#pragma unroll
        for (int s = 0; s < SPLITS; ++s) {
            wn[s] = exp2f(ms[s] - mstar);
            den = fmaf(wn[s], l_lds[s][qq], den);
        }
        float inv = 1.f / den;
#pragma unroll
        for (int s = 0; s < SPLITS; ++s) wn[s] *= inv;
        float a0 = 0.f, a1 = 0.f;
#pragma unroll
        for (int s = 0; s < SPLITS; ++s) {
            a0 = fmaf(wn[s], o_lds[s][2 * dp][qq], a0);
            a1 = fmaf(wn[s], o_lds[s][2 * dp + 1][qq], a1);
        }
        u32* dst = reinterpret_cast<u32*>(agg + ((size_t)b * NDIM + q0 + qq) * CLD);
        dst[dp] = pack_bf16x2(a0, a1);
    }
}

// ---------------- Kernel 3: MFMA output projection + BN4 + ReLU + residual ----------------
// grid (B*128, 2), block 256 = 4 waves. Wave: o-tile 32 x n-tile 32, K=32 -> 2 MFMA.
// D[row=o][col=n]: lane col = n (coalesced stores along n).
__global__ __launch_bounds__(256) void out_proj(
    const u16* __restrict__ agg, const float* __restrict__ wo,
    const float* __restrict__ b4s, const float* __restrict__ b4b,
    const float* __restrict__ b4m, const float* __restrict__ b4v,
    const float* __restrict__ x, const float* __restrict__ gamma,
    float* __restrict__ out)
{
    __shared__ float2 sbn[128];   // (inv, bias) for this block's 128 o's

    const int tid  = threadIdx.x;
    const int lane = tid & 63;
    const int w    = tid >> 6;
    const int b    = blockIdx.x >> 7;
    const int n0   = (blockIdx.x & 127) * 32;
    const int oy   = blockIdx.y;
    const int o0   = oy * 128 + w * 32;
    const int col  = lane & 31;
    const int hi   = lane >> 5;

    if (tid < 128) {
        int oo = oy * 128 + tid;
        float inv = b4s[oo] / sqrtf(b4v[oo] + EPSBN);
        sbn[tid] = make_float2(inv, b4b[oo] - b4m[oo] * inv);
    }
    __syncthreads();

    // A-frag: wo[o0+col][k], k = 8*hi+i (+16 for frag1); f32 -> bf16 pack
    const float* wp = wo + (size_t)(o0 + col) * CLD + 8 * hi;
    float4 wa = *reinterpret_cast<const float4*>(wp);
    float4 wb_ = *reinterpret_cast<const float4*>(wp + 4);
    float4 wc = *reinterpret_cast<const float4*>(wp + 16);
    float4 wd = *reinterpret_cast<const float4*>(wp + 20);
    bf16x8 wf0 = pack8(wa, wb_);
    bf16x8 wf1 = pack8(wc, wd);

    // B-frag: agg[b][n0+col][k], k = 8*hi+i (+16)
    const u16* ap = agg + ((size_t)b * NDIM + n0 + col) * CLD + 8 * hi;
    bf16x8 af0 = *reinterpret_cast<const bf16x8*>(ap);
    bf16x8 af1 = *reinterpret_cast<const bf16x8*>(ap + 16);

    f32x16 acc = {0.f,0.f,0.f,0.f, 0.f,0.f,0.f,0.f, 0.f,0.f,0.f,0.f, 0.f,0.f,0.f,0.f};
    acc = __builtin_amdgcn_mfma_f32_32x32x16_bf16(wf0, af0, acc, 0, 0, 0);
    acc = __builtin_amdgcn_mfma_f32_32x32x16_bf16(wf1, af1, acc, 0, 0, 0);

    const float gm = gamma[0];
#pragma unroll
    for (int r = 0; r < 16; ++r) {
        int j  = (r & 3) + 8 * (r >> 2) + 4 * hi;   // local o index
        float2 ib = sbn[w * 32 + j];                 // broadcast (uniform per half-wave)
        int oo = o0 + j;
        size_t idx = ((size_t)b * CDIM + oo) * NDIM + n0 + col;
        float y = fmaxf(fmaf(acc[r], ib.x, ib.y), 0.f);
        out[idx] = fmaf(gm, y, x[idx]);
    }
}

extern "C" void kernel_launch(void* const* d_in, const int* in_sizes, int n_in,
                              void* d_out, int out_size, void* d_ws, size_t ws_size,
                              hipStream_t stream) {
    const float* x   = (const float*)d_in[0];
    const float* w1  = (const float*)d_in[1];
    const float* w2  = (const float*)d_in[2];
    const float* w3  = (const float*)d_in[3];
    const float* wo  = (const float*)d_in[4];
    const float* b1s = (const float*)d_in[5];
    const float* b1b = (const float*)d_in[6];
    const float* b1m = (const float*)d_in[7];
    const float* b1v = (const float*)d_in[8];
    const float* b2s = (const float*)d_in[9];
    const float* b2b = (const float*)d_in[10];
    const float* b2m = (const float*)d_in[11];
    const float* b2v = (const float*)d_in[12];
    const float* b3s = (const float*)d_in[13];
    const float* b3b = (const float*)d_in[14];
    const float* b3m = (const float*)d_in[15];
    const float* b3v = (const float*)d_in[16];
    const float* b4s = (const float*)d_in[17];
    const float* b4b = (const float*)d_in[18];
    const float* b4m = (const float*)d_in[19];
    const float* b4v = (const float*)d_in[20];
    const float* gm  = (const float*)d_in[21];
    float* out = (float*)d_out;

    // ws layout (bytes):
    //   [0, 1MB)   : qbf bf16 [B][N][32]  (pre-scaled by log2e)
    //   [1MB, 2MB) : kbf bf16 [B][N][32]
    //   [2MB, 3MB) : vbf bf16 [B][32][N]
    //   [3MB, 4MB) : agg bf16 [B][N][32]
    char* W = (char*)d_ws;
    u16* qbf = (u16*)W;
    u16* kbf = (u16*)(W + (1u << 20));
    u16* vbf = (u16*)(W + (2u << 20));
    u16* agg = (u16*)(W + (3u << 20));

    dim3 gp(NDIM / 128, BATCH, 6);
    proj_qkv<<<gp, 256, 0, stream>>>(x, w1, w2, w3,
                                     b1s, b1b, b1m, b1v,
                                     b2s, b2b, b2m, b2v,
                                     b3s, b3b, b3m, b3v,
                                     qbf, kbf, vbf);

    dim3 ga(NDIM / 32, BATCH);
    attn_mfma<<<ga, 512, 0, stream>>>(qbf, kbf, vbf, agg);

    dim3 go(BATCH * 128, 2);
    out_proj<<<go, 256, 0, stream>>>(agg, wo, b4s, b4b, b4m, b4v, x, gm, out);
}

// Round 6
// 74.494 us; speedup vs baseline: 1.0263x; 1.0263x over previous
//
#include <hip/hip_runtime.h>
#include <hip/hip_bf16.h>
#include <math.h>

#define BATCH 4
#define CDIM 256
#define NDIM 4096
#define CLD 32
#define EPSBN 1e-5f
#define SPLITS 8
#define KEYS_PER_WAVE (NDIM / SPLITS)   // 512
#define LOG2E 1.4426950408889634f
#define DEFER_THR 8.0f

typedef unsigned short u16;
typedef unsigned int u32;
typedef __attribute__((ext_vector_type(8))) short bf16x8;   // 8 bf16 = 4 VGPR MFMA operand
typedef __attribute__((ext_vector_type(16))) float f32x16;  // 32x32 MFMA accumulator
typedef __attribute__((ext_vector_type(4))) u32 u32x4;

__device__ inline u16 f2bf(float x) {
    return __builtin_bit_cast(u16, __float2bfloat16(x));
}
__device__ inline u32 pack_bf16x2(float a, float b) {
    return (u32)f2bf(a) | ((u32)f2bf(b) << 16);
}
__device__ inline bf16x8 pack8(float4 a, float4 b) {
    u32x4 u;
    u.x = pack_bf16x2(a.x, a.y); u.y = pack_bf16x2(a.z, a.w);
    u.z = pack_bf16x2(b.x, b.y); u.w = pack_bf16x2(b.z, b.w);
    return __builtin_bit_cast(bf16x8, u);
}

// ---------------- Kernel 1: QKV projection + BN + ReLU -> bf16 ----------------
// grid (N/128, B, 3), block 256 = 4 waves (round-4 structure). Wave g = z*4+w
// owns 8 channels of one of {w1,w2,w3} x 128 n. Weights via uniform s_load.
// q (scaled by log2e), k -> [B][N][32] bf16 ; v -> [B][32][N'] bf16 where the
// key order within each 32-group is permuted by the involution kappa
// (n^=12 for (n>>2)&3 in {1,2}) so attention's PV B-operand needs no shuffles.
__global__ __launch_bounds__(256) void proj_qkv(
    const float* __restrict__ x,
    const float* __restrict__ w1, const float* __restrict__ w2, const float* __restrict__ w3,
    const float* __restrict__ b1s, const float* __restrict__ b1b, const float* __restrict__ b1m, const float* __restrict__ b1v,
    const float* __restrict__ b2s, const float* __restrict__ b2b, const float* __restrict__ b2m, const float* __restrict__ b2v,
    const float* __restrict__ b3s, const float* __restrict__ b3b, const float* __restrict__ b3m, const float* __restrict__ b3v,
    u16* __restrict__ qo, u16* __restrict__ ko, u16* __restrict__ vo)
{
    const int tid  = threadIdx.x;
    const int lane = tid & 63;
    const int b    = blockIdx.y;
    const int g    = __builtin_amdgcn_readfirstlane(blockIdx.z * 4 + (tid >> 6)); // 0..11 uniform
    const int mat  = g >> 2;             // 0:q/w1 1:k/w2 2:v/w3
    const int ch0  = (g & 3) * 8;
    const int n    = blockIdx.x * 128 + lane * 2;

    const float* wb = ((mat == 0) ? w1 : (mat == 1) ? w2 : w3) + (size_t)ch0 * CDIM;

    float2 acc[8];
#pragma unroll
    for (int o = 0; o < 8; ++o) acc[o] = make_float2(0.f, 0.f);

    const float* xb = x + (size_t)b * CDIM * NDIM + n;

#pragma unroll 2
    for (int c = 0; c < CDIM; c += 4) {
        float4 wq[8];
#pragma unroll
        for (int o = 0; o < 8; ++o)
            wq[o] = *reinterpret_cast<const float4*>(wb + o * CDIM + c);  // uniform -> s_load
        float2 xv[4];
#pragma unroll
        for (int cc = 0; cc < 4; ++cc)
            xv[cc] = *reinterpret_cast<const float2*>(xb + (size_t)(c + cc) * NDIM);
#pragma unroll
        for (int cc = 0; cc < 4; ++cc) {
#pragma unroll
            for (int o = 0; o < 8; ++o) {
                float wv = (cc == 0) ? wq[o].x : (cc == 1) ? wq[o].y : (cc == 2) ? wq[o].z : wq[o].w;
                acc[o].x = fmaf(wv, xv[cc].x, acc[o].x);
                acc[o].y = fmaf(wv, xv[cc].y, acc[o].y);
            }
        }
    }

    const float* ps = (mat == 0) ? b1s : (mat == 1) ? b2s : b3s;
    const float* pb = (mat == 0) ? b1b : (mat == 1) ? b2b : b3b;
    const float* pm = (mat == 0) ? b1m : (mat == 1) ? b2m : b3m;
    const float* pv = (mat == 0) ? b1v : (mat == 1) ? b2v : b3v;
    const float qscale = (mat == 0) ? LOG2E : 1.0f;

    float y0[8], y1[8];
#pragma unroll
    for (int o = 0; o < 8; ++o) {
        float inv = ps[ch0 + o] / sqrtf(pv[ch0 + o] + EPSBN);
        float mb  = pm[ch0 + o];
        float bb  = pb[ch0 + o];
        y0[o] = fmaxf((acc[o].x - mb) * inv + bb, 0.f) * qscale;
        y1[o] = fmaxf((acc[o].y - mb) * inv + bb, 0.f) * qscale;
    }

    if (mat < 2) {
        u16* dst = ((mat == 0) ? qo : ko) + ((size_t)b * NDIM + n) * CLD + ch0;
        u32x4 s0, s1;
        s0.x = pack_bf16x2(y0[0], y0[1]); s0.y = pack_bf16x2(y0[2], y0[3]);
        s0.z = pack_bf16x2(y0[4], y0[5]); s0.w = pack_bf16x2(y0[6], y0[7]);
        s1.x = pack_bf16x2(y1[0], y1[1]); s1.y = pack_bf16x2(y1[2], y1[3]);
        s1.z = pack_bf16x2(y1[4], y1[5]); s1.w = pack_bf16x2(y1[6], y1[7]);
        *reinterpret_cast<u32x4*>(dst)       = s0;
        *reinterpret_cast<u32x4*>(dst + CLD) = s1;
    } else {
        // kappa permutation of the pair's column (pairs move intact: n even)
        int q2 = (n >> 2) & 3;
        int np = (q2 == 1 || q2 == 2) ? (n ^ 12) : n;
#pragma unroll
        for (int o = 0; o < 8; ++o)
            *reinterpret_cast<u32*>(vo + ((size_t)b * CLD + ch0 + o) * NDIM + np) = pack_bf16x2(y0[o], y1[o]);
    }
}

// ---------------- Kernel 2: MFMA flash attention, 8-way split-in-block ----------------
// grid (N/32, B), block 512 = 8 waves; all waves share one 32-query tile, each
// owns 512 keys. Scores in log2 domain (q pre-scaled by log2e). V is stored
// kappa-permuted, so P fragments come directly from accumulator registers.
// Defer-max (THR=8): skip O-rescale while tile max grows < 8 in log2 domain.
// LDS combine writes agg bf16 [B][N][32].
__global__ __launch_bounds__(512, 4) void attn_mfma(
    const u16* __restrict__ q, const u16* __restrict__ k, const u16* __restrict__ v,
    u16* __restrict__ agg)
{
    __shared__ float o_lds[SPLITS][32][32];   // 32 KB
    __shared__ float m_lds[SPLITS][32];
    __shared__ float l_lds[SPLITS][32];

    const int tid  = threadIdx.x;
    const int lane = tid & 63;
    const int w    = tid >> 6;            // split 0..7
    const int b    = blockIdx.y;
    const int q0   = blockIdx.x * 32;
    const int col  = lane & 31;
    const int hi   = lane >> 5;

    const u16* qp = q + ((size_t)b * NDIM + q0 + col) * CLD + 8 * hi;
    bf16x8 qf0 = *reinterpret_cast<const bf16x8*>(qp);
    bf16x8 qf1 = *reinterpret_cast<const bf16x8*>(qp + 16);

    f32x16 o = {0.f,0.f,0.f,0.f, 0.f,0.f,0.f,0.f, 0.f,0.f,0.f,0.f, 0.f,0.f,0.f,0.f};
    float m_run = -3e38f, l_run = 0.f;

    const int kstart = w * KEYS_PER_WAVE;
    const u16* kb = k + (size_t)b * NDIM * CLD;
    const u16* vb = v + (size_t)b * CLD * NDIM + (size_t)col * NDIM;

    for (int kt = 0; kt < KEYS_PER_WAVE; kt += 64) {
        const int k0 = kstart + kt;
        // ---- QK^T for two 32-key tiles ----
        const u16* kpA = kb + (size_t)(k0 + col) * CLD + 8 * hi;
        bf16x8 kfA0 = *reinterpret_cast<const bf16x8*>(kpA);
        bf16x8 kfA1 = *reinterpret_cast<const bf16x8*>(kpA + 16);
        const u16* kpB = kpA + 32 * CLD;
        bf16x8 kfB0 = *reinterpret_cast<const bf16x8*>(kpB);
        bf16x8 kfB1 = *reinterpret_cast<const bf16x8*>(kpB + 16);

        f32x16 sa = {0.f,0.f,0.f,0.f, 0.f,0.f,0.f,0.f, 0.f,0.f,0.f,0.f, 0.f,0.f,0.f,0.f};
        f32x16 sb = {0.f,0.f,0.f,0.f, 0.f,0.f,0.f,0.f, 0.f,0.f,0.f,0.f, 0.f,0.f,0.f,0.f};
        sa = __builtin_amdgcn_mfma_f32_32x32x16_bf16(kfA0, qf0, sa, 0, 0, 0);
        sa = __builtin_amdgcn_mfma_f32_32x32x16_bf16(kfA1, qf1, sa, 0, 0, 0);
        sb = __builtin_amdgcn_mfma_f32_32x32x16_bf16(kfB0, qf0, sb, 0, 0, 0);
        sb = __builtin_amdgcn_mfma_f32_32x32x16_bf16(kfB1, qf1, sb, 0, 0, 0);

        // ---- online softmax over 64 keys (log2 domain, defer-max THR=8) ----
        float tmax = fmaxf(sa[0], sb[0]);
#pragma unroll
        for (int r = 1; r < 16; ++r) tmax = fmaxf(tmax, fmaxf(sa[r], sb[r]));
        tmax = fmaxf(tmax, __shfl_xor(tmax, 32));

        if (__any(tmax > m_run + DEFER_THR)) {
            float mnew = fmaxf(m_run, tmax);
            float f = exp2f(m_run - mnew);
            l_run *= f;
            m_run = mnew;
#pragma unroll
            for (int r = 0; r < 16; ++r) o[r] *= f;
        }

        float psum = 0.f;
#pragma unroll
        for (int r = 0; r < 16; ++r) { sa[r] = exp2f(sa[r] - m_run); psum += sa[r]; }
#pragma unroll
        for (int r = 0; r < 16; ++r) { sb[r] = exp2f(sb[r] - m_run); psum += sb[r]; }
        psum += __shfl_xor(psum, 32);
        l_run += psum;

        // ---- P fragments direct from accumulator (V kappa-permuted) ----
        u32x4 pa0, pa1, pb0, pb1;
        pa0.x = pack_bf16x2(sa[0],  sa[1]);  pa0.y = pack_bf16x2(sa[2],  sa[3]);
        pa0.z = pack_bf16x2(sa[4],  sa[5]);  pa0.w = pack_bf16x2(sa[6],  sa[7]);
        pa1.x = pack_bf16x2(sa[8],  sa[9]);  pa1.y = pack_bf16x2(sa[10], sa[11]);
        pa1.z = pack_bf16x2(sa[12], sa[13]); pa1.w = pack_bf16x2(sa[14], sa[15]);
        pb0.x = pack_bf16x2(sb[0],  sb[1]);  pb0.y = pack_bf16x2(sb[2],  sb[3]);
        pb0.z = pack_bf16x2(sb[4],  sb[5]);  pb0.w = pack_bf16x2(sb[6],  sb[7]);
        pb1.x = pack_bf16x2(sb[8],  sb[9]);  pb1.y = pack_bf16x2(sb[10], sb[11]);
        pb1.z = pack_bf16x2(sb[12], sb[13]); pb1.w = pack_bf16x2(sb[14], sb[15]);

        // ---- PV for both tiles ----
        const u16* vp = vb + k0 + 8 * hi;
        bf16x8 vfA0 = *reinterpret_cast<const bf16x8*>(vp);
        bf16x8 vfA1 = *reinterpret_cast<const bf16x8*>(vp + 16);
        bf16x8 vfB0 = *reinterpret_cast<const bf16x8*>(vp + 32);
        bf16x8 vfB1 = *reinterpret_cast<const bf16x8*>(vp + 48);

        o = __builtin_amdgcn_mfma_f32_32x32x16_bf16(vfA0, __builtin_bit_cast(bf16x8, pa0), o, 0, 0, 0);
        o = __builtin_amdgcn_mfma_f32_32x32x16_bf16(vfA1, __builtin_bit_cast(bf16x8, pa1), o, 0, 0, 0);
        o = __builtin_amdgcn_mfma_f32_32x32x16_bf16(vfB0, __builtin_bit_cast(bf16x8, pb0), o, 0, 0, 0);
        o = __builtin_amdgcn_mfma_f32_32x32x16_bf16(vfB1, __builtin_bit_cast(bf16x8, pb1), o, 0, 0, 0);
    }

    // ---- publish partials ----
#pragma unroll
    for (int r = 0; r < 16; ++r) {
        int d = (r & 3) + 8 * (r >> 2) + 4 * hi;
        o_lds[w][d][col] = o[r];
    }
    if (hi == 0) { m_lds[w][col] = m_run; l_lds[w][col] = l_run; }
    __syncthreads();

    // ---- combine 8 splits -> agg bf16 [B][N][32] ----
    {
        const int qq = tid >> 4;
        const int dp = tid & 15;
        float ms[SPLITS];
        float mstar = -3e38f;
#pragma unroll
        for (int s = 0; s < SPLITS; ++s) { ms[s] = m_lds[s][qq]; mstar = fmaxf(mstar, ms[s]); }
        float wn[SPLITS];
        float den = 0.f;
#pragma unroll
        for (int s = 0; s < SPLITS; ++s) {
            wn[s] = exp2f(ms[s] - mstar);
            den = fmaf(wn[s], l_lds[s][qq], den);
        }
        float inv = 1.f / den;
#pragma unroll
        for (int s = 0; s < SPLITS; ++s) wn[s] *= inv;
        float a0 = 0.f, a1 = 0.f;
#pragma unroll
        for (int s = 0; s < SPLITS; ++s) {
            a0 = fmaf(wn[s], o_lds[s][2 * dp][qq], a0);
            a1 = fmaf(wn[s], o_lds[s][2 * dp + 1][qq], a1);
        }
        u32* dst = reinterpret_cast<u32*>(agg + ((size_t)b * NDIM + q0 + qq) * CLD);
        dst[dp] = pack_bf16x2(a0, a1);
    }
}

// ---------------- Kernel 3: MFMA output projection + BN4 + ReLU + residual ----------------
// grid (B*128, 2), block 256 = 4 waves. Wave: o-tile 32 x n-tile 32, K=32 -> 2 MFMA.
__global__ __launch_bounds__(256) void out_proj(
    const u16* __restrict__ agg, const float* __restrict__ wo,
    const float* __restrict__ b4s, const float* __restrict__ b4b,
    const float* __restrict__ b4m, const float* __restrict__ b4v,
    const float* __restrict__ x, const float* __restrict__ gamma,
    float* __restrict__ out)
{
    __shared__ float2 sbn[128];   // (inv, bias) for this block's 128 o's

    const int tid  = threadIdx.x;
    const int lane = tid & 63;
    const int w    = tid >> 6;
    const int b    = blockIdx.x >> 7;
    const int n0   = (blockIdx.x & 127) * 32;
    const int oy   = blockIdx.y;
    const int o0   = oy * 128 + w * 32;
    const int col  = lane & 31;
    const int hi   = lane >> 5;

    if (tid < 128) {
        int oo = oy * 128 + tid;
        float inv = b4s[oo] / sqrtf(b4v[oo] + EPSBN);
        sbn[tid] = make_float2(inv, b4b[oo] - b4m[oo] * inv);
    }
    __syncthreads();

    // A-frag: wo[o0+col][k], k = 8*hi+i (+16 for frag1); f32 -> bf16 pack
    const float* wp = wo + (size_t)(o0 + col) * CLD + 8 * hi;
    float4 wa = *reinterpret_cast<const float4*>(wp);
    float4 wb_ = *reinterpret_cast<const float4*>(wp + 4);
    float4 wc = *reinterpret_cast<const float4*>(wp + 16);
    float4 wd = *reinterpret_cast<const float4*>(wp + 20);
    bf16x8 wf0 = pack8(wa, wb_);
    bf16x8 wf1 = pack8(wc, wd);

    // B-frag: agg[b][n0+col][k], k = 8*hi+i (+16)
    const u16* ap = agg + ((size_t)b * NDIM + n0 + col) * CLD + 8 * hi;
    bf16x8 af0 = *reinterpret_cast<const bf16x8*>(ap);
    bf16x8 af1 = *reinterpret_cast<const bf16x8*>(ap + 16);

    f32x16 acc = {0.f,0.f,0.f,0.f, 0.f,0.f,0.f,0.f, 0.f,0.f,0.f,0.f, 0.f,0.f,0.f,0.f};
    acc = __builtin_amdgcn_mfma_f32_32x32x16_bf16(wf0, af0, acc, 0, 0, 0);
    acc = __builtin_amdgcn_mfma_f32_32x32x16_bf16(wf1, af1, acc, 0, 0, 0);

    const float gm = gamma[0];
#pragma unroll
    for (int r = 0; r < 16; ++r) {
        int j  = (r & 3) + 8 * (r >> 2) + 4 * hi;   // local o index
        float2 ib = sbn[w * 32 + j];
        int oo = o0 + j;
        size_t idx = ((size_t)b * CDIM + oo) * NDIM + n0 + col;
        float y = fmaxf(fmaf(acc[r], ib.x, ib.y), 0.f);
        out[idx] = fmaf(gm, y, x[idx]);
    }
}

extern "C" void kernel_launch(void* const* d_in, const int* in_sizes, int n_in,
                              void* d_out, int out_size, void* d_ws, size_t ws_size,
                              hipStream_t stream) {
    const float* x   = (const float*)d_in[0];
    const float* w1  = (const float*)d_in[1];
    const float* w2  = (const float*)d_in[2];
    const float* w3  = (const float*)d_in[3];
    const float* wo  = (const float*)d_in[4];
    const float* b1s = (const float*)d_in[5];
    const float* b1b = (const float*)d_in[6];
    const float* b1m = (const float*)d_in[7];
    const float* b1v = (const float*)d_in[8];
    const float* b2s = (const float*)d_in[9];
    const float* b2b = (const float*)d_in[10];
    const float* b2m = (const float*)d_in[11];
    const float* b2v = (const float*)d_in[12];
    const float* b3s = (const float*)d_in[13];
    const float* b3b = (const float*)d_in[14];
    const float* b3m = (const float*)d_in[15];
    const float* b3v = (const float*)d_in[16];
    const float* b4s = (const float*)d_in[17];
    const float* b4b = (const float*)d_in[18];
    const float* b4m = (const float*)d_in[19];
    const float* b4v = (const float*)d_in[20];
    const float* gm  = (const float*)d_in[21];
    float* out = (float*)d_out;

    // ws layout (bytes):
    //   [0, 1MB)   : qbf bf16 [B][N][32]  (pre-scaled by log2e)
    //   [1MB, 2MB) : kbf bf16 [B][N][32]
    //   [2MB, 3MB) : vbf bf16 [B][32][N]  (kappa-permuted key order)
    //   [3MB, 4MB) : agg bf16 [B][N][32]
    char* W = (char*)d_ws;
    u16* qbf = (u16*)W;
    u16* kbf = (u16*)(W + (1u << 20));
    u16* vbf = (u16*)(W + (2u << 20));
    u16* agg = (u16*)(W + (3u << 20));

    dim3 gp(NDIM / 128, BATCH, 3);
    proj_qkv<<<gp, 256, 0, stream>>>(x, w1, w2, w3,
                                     b1s, b1b, b1m, b1v,
                                     b2s, b2b, b2m, b2v,
                                     b3s, b3b, b3m, b3v,
                                     qbf, kbf, vbf);

    dim3 ga(NDIM / 32, BATCH);
    attn_mfma<<<ga, 512, 0, stream>>>(qbf, kbf, vbf, agg);

    dim3 go(BATCH * 128, 2);
    out_proj<<<go, 256, 0, stream>>>(agg, wo, b4s, b4b, b4m, b4v, x, gm, out);
}